// Round 2
// baseline (450.916 us; speedup 1.0000x reference)
//
#include <hip/hip_runtime.h>

// Problem: B=1, L=768, D_SINGLE=384, D_PAIR=128
//   left  = s @ W[:384]    (768 x 128)
//   right = s @ W[384:]    (768 x 128)
//   out[i,j,f] = left[i,f] + right[j,f] + bias[f]   -> (1,768,768,128) fp32
// z (d_in[1]) is UNUSED by the reference.

#define L_DIM   768
#define D_S     384
#define D_P     128

// clang-native vector type: __builtin_nontemporal_store requires a real
// vector type, not HIP's float4 class.
typedef float f32x4 __attribute__((ext_vector_type(4)));

// ---------------- Kernel A: projection -------------------------------------
// 4 rows per block, 256 threads = 4 waves; wave r handles row l0+r.
// Lane c (0..63) computes one float4 of the 256-wide (left|right) row:
//   c <  32 : left  f4 = c      (bias folded in)
//   c >= 32 : right f4 = c - 32
// W is read as float4 (coalesced) and amortized over 4 rows -> L2 traffic
// drops 302 MB -> 75 MB vs the 1-row/block version.
__global__ __launch_bounds__(256) void proj_kernel(
    const float4* __restrict__ s4,     // (768, 96)  float4 view of s (768,384)
    const float4* __restrict__ W4,     // (768, 32)  float4 view of W (768,128)
    const float4* __restrict__ bias4,  // (32,)
    float4* __restrict__ proj4)        // (768, 64)  [left(32) | right(32)]
{
    __shared__ float s_rows[4][D_S];   // 6 KB
    const int tid = threadIdx.x;
    const int r   = tid >> 6;          // wave id = row within block
    const int c   = tid & 63;          // lane    = f4 column
    const int l0  = blockIdx.x * 4;

    // stage 4 s-rows (1536 floats = 384 float4), fully coalesced
    {
        const float4* src = s4 + (size_t)l0 * (D_S / 4);
        float4* dst = (float4*)&s_rows[0][0];
        for (int idx = tid; idx < 4 * (D_S / 4); idx += 256) dst[idx] = src[idx];
    }
    __syncthreads();

    const int     right = (c >= 32);
    const int     f4    = c & 31;
    const float4* Wb    = W4 + (size_t)(right ? D_S : 0) * (D_P / 4) + f4;
    const float*  srow  = s_rows[r];   // wave-uniform -> LDS broadcast reads

    float4 acc = right ? make_float4(0.f, 0.f, 0.f, 0.f) : bias4[f4];

#pragma unroll 8
    for (int d = 0; d < D_S; ++d) {
        const float  sv = srow[d];
        const float4 w  = Wb[(size_t)d * (D_P / 4)];
        acc.x = fmaf(sv, w.x, acc.x);
        acc.y = fmaf(sv, w.y, acc.y);
        acc.z = fmaf(sv, w.z, acc.z);
        acc.w = fmaf(sv, w.w, acc.w);
    }
    proj4[(size_t)(l0 + r) * 64 + c] = acc;
}

// ---------------- Kernel B: outer broadcast sum ----------------------------
// grid = (768/32, 768), block = 256. blockIdx.y = i; each block covers 32 j.
// Thread: f4 = tid&31, jg = tid>>5 (0..7); handles JPT=4 consecutive j's.
// lv loaded once per thread; stores are nontemporal so the 302 MB output
// stream does not evict proj (786 KB) from L2.
#define JPT 4
__global__ __launch_bounds__(256) void outer_kernel(
    const float4* __restrict__ proj4,  // (768, 64)
    float4* __restrict__ out4)         // (768*768*32) float4
{
    const int i   = blockIdx.y;
    const int tid = threadIdx.x;
    const int f4  = tid & 31;
    const int jg  = tid >> 5;                       // 0..7
    const int j0  = blockIdx.x * (8 * JPT) + jg * JPT;

    const float4 lv = proj4[(size_t)i * 64 + f4];   // left row (L1/L2 hit)
    f32x4* obase = (f32x4*)(out4 + ((size_t)i * L_DIM + j0) * (D_P / 4) + f4);

#pragma unroll
    for (int k = 0; k < JPT; ++k) {
        const float4 rv = proj4[(size_t)(j0 + k) * 64 + 32 + f4];
        f32x4 o;
        o.x = lv.x + rv.x;
        o.y = lv.y + rv.y;
        o.z = lv.z + rv.z;
        o.w = lv.w + rv.w;
        __builtin_nontemporal_store(o, obase + (size_t)k * (D_P / 4));
    }
}

extern "C" void kernel_launch(void* const* d_in, const int* in_sizes, int n_in,
                              void* d_out, int out_size, void* d_ws, size_t ws_size,
                              hipStream_t stream) {
    const float* s    = (const float*)d_in[0];
    // d_in[1] = z, unused by the reference
    const float* W    = (const float*)d_in[2];
    const float* bias = (const float*)d_in[3];
    float* out  = (float*)d_out;
    float* proj = (float*)d_ws;   // 768*256 floats = 786 KB

    proj_kernel<<<dim3(L_DIM / 4), dim3(256), 0, stream>>>(
        (const float4*)s, (const float4*)W, (const float4*)bias, (float4*)proj);

    outer_kernel<<<dim3(L_DIM / (8 * JPT), L_DIM), dim3(256), 0, stream>>>(
        (const float4*)proj, (float4*)out);
}

// Round 3
// 440.231 us; speedup vs baseline: 1.0243x; 1.0243x over previous
//
#include <hip/hip_runtime.h>

// Problem: B=1, L=768, D_SINGLE=384, D_PAIR=128
//   left  = s @ W[:384]    (768 x 128)
//   right = s @ W[384:]    (768 x 128)
//   out[i,j,f] = left[i,f] + right[j,f] + bias[f]   -> (1,768,768,128) fp32
// z (d_in[1]) is UNUSED by the reference.

#define L_DIM   768
#define D_S     384
#define D_P     128

// ---------------- Kernel A: projection -------------------------------------
// grid = (384), block = (256). Block b handles rows 2b, 2b+1.
// threadIdx.x = f in [0,256): f<128 -> left column fc=f (bias folded),
// f>=128 -> right column fc=f-128. Each thread streams one W column once
// and applies it to BOTH rows -> W L2 traffic halves vs 1 row/block
// (302 MB -> 151 MB) at unchanged coalescing (512 B per half-wave per d).
__global__ __launch_bounds__(256) void proj_kernel(
    const float* __restrict__ s,     // (768, 384)
    const float* __restrict__ W,     // (768, 128)
    const float* __restrict__ bias,  // (128,)
    float* __restrict__ proj)        // (768, 256)
{
    __shared__ float s_rows[2][D_S];
    const int l0 = blockIdx.x * 2;
    const int f  = threadIdx.x;

    // stage 2 s rows (3 KB) into LDS, coalesced
    for (int d = threadIdx.x; d < 2 * D_S; d += 256)
        s_rows[0][d] = s[l0 * D_S + d];   // [2][D_S] is contiguous
    __syncthreads();

    const int fc = f & (D_P - 1);
    const float* Wbase = W + ((f >= D_P) ? (D_S * D_P) : 0) + fc;

    const float binit = (f < D_P) ? bias[fc] : 0.0f;  // bias folded into left
    float acc0 = binit;
    float acc1 = binit;
#pragma unroll 8
    for (int d = 0; d < D_S; ++d) {
        const float w = Wbase[(size_t)d * D_P];
        acc0 = fmaf(s_rows[0][d], w, acc0);
        acc1 = fmaf(s_rows[1][d], w, acc1);
    }
    proj[(size_t)l0 * 256 + f]       = acc0;
    proj[(size_t)(l0 + 1) * 256 + f] = acc1;
}

// ---------------- Kernel B: outer broadcast sum ----------------------------
// EXACT round-0 structure (measured ~52 us, ~90% of the 302 MB write floor).
// grid = (96, 768), block = 256. blockIdx.y = i.
// t = blockIdx.x*256 + tid in [0, 768*32): f4 = t & 31, j = t >> 5.
// Plain stores: the L2/L3 write path streams at full HBM BW; nontemporal
// stores measured SLOWER (round 2, +~15 us).
__global__ __launch_bounds__(256) void outer_kernel(
    const float4* __restrict__ proj4,  // (768, 64) float4 view of proj
    float4* __restrict__ out4)         // (768*768*32) float4
{
    const int i  = blockIdx.y;
    const int t  = blockIdx.x * 256 + threadIdx.x;  // [0, 24576)
    const int f4 = t & 31;
    const int j  = t >> 5;

    const float4 lv = proj4[i * 64 + f4];        // left row, L1-broadcast
    const float4 rv = proj4[j * 64 + 32 + f4];   // right row

    float4 o;
    o.x = lv.x + rv.x;
    o.y = lv.y + rv.y;
    o.z = lv.z + rv.z;
    o.w = lv.w + rv.w;

    out4[(size_t)i * (L_DIM * (D_P / 4)) + t] = o;
}

extern "C" void kernel_launch(void* const* d_in, const int* in_sizes, int n_in,
                              void* d_out, int out_size, void* d_ws, size_t ws_size,
                              hipStream_t stream) {
    const float* s    = (const float*)d_in[0];
    // d_in[1] = z, unused by the reference
    const float* W    = (const float*)d_in[2];
    const float* bias = (const float*)d_in[3];
    float* out  = (float*)d_out;
    float* proj = (float*)d_ws;   // 768*256 floats = 786 KB

    proj_kernel<<<dim3(L_DIM / 2), dim3(256), 0, stream>>>(s, W, bias, proj);

    outer_kernel<<<dim3(L_DIM * (D_P / 4) / 256, L_DIM), dim3(256), 0, stream>>>(
        (const float4*)proj, (float4*)out);
}